// Round 1
// baseline (699.083 us; speedup 1.0000x reference)
//
#include <hip/hip_runtime.h>
#include <hip/hip_bf16.h>

#define NN 100000
#define HH 64
#define AN 92
#define NSTEP 8
#define NGRP 6250          // NN / 16, exact
#define NB 391             // ceil(NN / 256)
#define RB 768             // reduce-part persistent blocks (3/CU: frees 20 wave-slots/CU for place overlap)
#define SPMAX 4608         // staged srt entries per aggr block (mean span 2048, +45 sigma safe)

typedef float f4v __attribute__((ext_vector_type(4)));
typedef short s8v __attribute__((ext_vector_type(8)));

__device__ __forceinline__ float sigf(float x) { return 1.0f / (1.0f + __expf(-x)); }
// tanh(x) = 1 - 2/(1+e^{2x}); saturates correctly, no NaN.
__device__ __forceinline__ float tanhfast(float x) { return 1.0f - 2.0f / (1.0f + __expf(2.0f * x)); }

__device__ __forceinline__ unsigned short tobf(float x) {
    __hip_bfloat16 b = __float2bfloat16(x);   // RNE
    return __builtin_bit_cast(unsigned short, b);
}
__device__ __forceinline__ float frombf(unsigned short u) {
    return __int_as_float(((unsigned)u) << 16);
}

// ---------------------------------------------------------------------------
// hb / Sb CHUNK LAYOUT (R18): [8][NN][8] bf16. Chunk cg holds columns
// cg*8 .. cg*8+7 of every node (16 B per node, 1.6 MB per chunk-table).
// k_aggr block cg = blockIdx&7 matches HW XCD round-robin (dispatch%8=XCD,
// the same assumption behind the m157 chiplet swizzle) so each XCD's random
// gathers stay inside its own L2-resident 1.6 MB slice instead of thrashing
// a 12.8 MB row-major table through L3 (~100 MB/step -> ~13 MB/step).
// ---------------------------------------------------------------------------

// Packed B-fragment position for mfma_f32_16x16x32_bf16:
// element B[k][r] lives at ((T*2+kh)*64 + lane)*8 + j,
// T=r>>4, kh=k>>5, lane=((k>>3)&3)*16 + (r&15), j=k&7.
__device__ __forceinline__ int packpos(int k, int r) {
    int T = r >> 4, kh = k >> 5;
    int lane = ((k >> 3) & 3) * 16 + (r & 15);
    int j = k & 7;
    return ((T * 2 + kh) * 64 + lane) * 8 + j;
}

// FUSED: k_hist (blocks 0..HB-1, FIRST: scan chain depends on it) +
// k_wc (next 384) + k_whp (last 48). Weights aren't needed until first gru.
__global__ __launch_bounds__(256) void k_histwcp(const int* __restrict__ dst,
                                                 int* __restrict__ cur, int E, int HB,
                                                 const float* __restrict__ Wg,
                                                 const float* __restrict__ w_ih,
                                                 const float* __restrict__ w_hh,
                                                 unsigned short* __restrict__ Wcp,
                                                 unsigned short* __restrict__ Whp) {
    __shared__ float wl[192 * 65];
    if (blockIdx.x < HB) {
        int e = blockIdx.x * 256 + threadIdx.x;
        if (e < E) atomicAdd(cur + dst[e], 1);
        return;
    }
    int wb = blockIdx.x - HB;
    if (wb < 384) {
        for (int i = threadIdx.x; i < 192 * 64; i += 256) {
            int r = i >> 6, q = i & 63;
            wl[r * 65 + q] = w_ih[i];
        }
        __syncthreads();
        int gid = wb * 256 + threadIdx.x;
        int r = gid % 192;
        int k = (gid / 192) & 63;
        int t = gid / (192 * 64);
        const float* wg = Wg + t * 4096 + k * 64;
        float acc = 0.f;
#pragma unroll
        for (int q = 0; q < 64; ++q) acc = fmaf(wg[q], wl[r * 65 + q], acc);
        Wcp[t * 12288 + packpos(k, r)] = tobf(acc);
    } else {
        int gid = (wb - 384) * 256 + threadIdx.x;
        if (gid >= 192 * 64) return;
        int r = gid >> 6, k = gid & 63;
        Whp[packpos(k, r)] = tobf(w_hh[r * 64 + k]);
    }
}

// ---- 2-phase exclusive scan of cur[0..NN) (bsum stays read-only) ----
__global__ __launch_bounds__(256) void k_scan1(const int* __restrict__ cur, int* __restrict__ bsum) {
    __shared__ int ws[4];
    int gid = blockIdx.x * 256 + threadIdx.x;
    int lane = threadIdx.x & 63, wave = threadIdx.x >> 6;
    int v = (gid < NN) ? cur[gid] : 0;
#pragma unroll
    for (int off = 32; off > 0; off >>= 1) v += __shfl_xor(v, off, 64);
    if (lane == 0) ws[wave] = v;
    __syncthreads();
    if (threadIdx.x == 0) bsum[blockIdx.x] = ws[0] + ws[1] + ws[2] + ws[3];
}

// scan3': each block redundantly sums bsum[0..blockIdx) (<=391 ints, cheap),
// then in-block shuffle scan. Removes the separate scan2 kernel.
__global__ __launch_bounds__(256) void k_scan3(int* __restrict__ cur, const int* __restrict__ bsum) {
    __shared__ int ws[4];
    __shared__ int ws2[4];
    int tid = threadIdx.x;
    int lane = tid & 63, wave = tid >> 6;
    // base = sum of bsum[0..blockIdx)
    int s = 0;
    for (int i = tid; i < blockIdx.x; i += 256) s += bsum[i];
#pragma unroll
    for (int off = 32; off > 0; off >>= 1) s += __shfl_xor(s, off, 64);
    if (lane == 0) ws2[wave] = s;
    // per-element scan
    int gid = blockIdx.x * 256 + tid;
    int orig = (gid < NN) ? cur[gid] : 0;
    int v = orig;
#pragma unroll
    for (int off = 1; off < 64; off <<= 1) {
        int w = __shfl_up(v, off, 64);
        if (lane >= off) v += w;
    }
    if (lane == 63) ws[wave] = v;
    __syncthreads();
    int base = ws2[0] + ws2[1] + ws2[2] + ws2[3];
    int woff = 0;
    for (int w = 0; w < 4; ++w) woff += (w < wave) ? ws[w] : 0;
    if (gid < NN) cur[gid] = v - orig + woff + base;
}

// FUSED: k_reduce (blocks 0..RB-1, FIRST — compute-heavy persistent blocks
// hold the CUs while memory-bound place blocks backfill; R14 proved
// place-first serializes) + k_place (blocks RB..RB+PB-1).
__global__ __launch_bounds__(256) void k_plred(const int* __restrict__ src,
                                               const int* __restrict__ dst,
                                               int* __restrict__ cur,
                                               int* __restrict__ srt, int E,
                                               const float* __restrict__ x,
                                               const float* __restrict__ W,
                                               const float* __restrict__ b,
                                               float* __restrict__ h,
                                               unsigned short* __restrict__ hb) {
    __shared__ float xl[16][96];      // k padded to 96, pads zeroed once
    __shared__ float wl[96 * 64];     // wl[k*64+j] = W[k][j]; k=92..95 zeroed
    int tid = threadIdx.x;
    if (blockIdx.x >= RB) {
        // ---- place branch ----
        int e = (blockIdx.x - RB) * 256 + tid;
        if (e < E) {
            int pos = atomicAdd(cur + dst[e], 1);
            srt[pos] = src[e];
        }
        return;
    }
    // ---- reduce branch (persistent over NGRP groups) ----
    for (int i = tid; i < AN * 64; i += 256) wl[i] = W[i];
    wl[AN * 64 + tid] = 0.f;                       // zero k=92..95 (4*64=256)
    if (tid < 64) xl[tid >> 2][AN + (tid & 3)] = 0.f;   // zero x pads (persist)
    int lane = tid & 63, wave = tid >> 6;
    float bj = b[lane];

    for (int g = blockIdx.x; g < NGRP; g += RB) {
        int n0 = g * 16;
        __syncthreads();   // xl from previous group fully consumed
        for (int i = tid; i < 16 * AN; i += 256)
            xl[i / AN][i % AN] = x[(size_t)n0 * AN + i];
        __syncthreads();
        float a[4];
#pragma unroll
        for (int u = 0; u < 4; ++u) a[u] = bj;
#pragma unroll
        for (int k4 = 0; k4 < 96; k4 += 4) {
            float4 xv[4];
#pragma unroll
            for (int u = 0; u < 4; ++u) xv[u] = *(const float4*)&xl[wave * 4 + u][k4];
#pragma unroll
            for (int kk = 0; kk < 4; ++kk) {
                float wv = wl[(k4 + kk) * 64 + lane];
                a[0] = fmaf(((const float*)&xv[0])[kk], wv, a[0]);
                a[1] = fmaf(((const float*)&xv[1])[kk], wv, a[1]);
                a[2] = fmaf(((const float*)&xv[2])[kk], wv, a[2]);
                a[3] = fmaf(((const float*)&xv[3])[kk], wv, a[3]);
            }
        }
#pragma unroll
        for (int u = 0; u < 4; ++u) {
            int n = n0 + wave * 4 + u;
            h[(size_t)n * HH + lane] = a[u];
            // chunked hb layout [8][NN][8]
            hb[((size_t)(lane >> 3) * NN + n) * 8 + (lane & 7)] = tobf(a[u]);
        }
    }
}

// R18 aggregation: XCD-sharded column chunks.
// Block cg = blockIdx&7 gathers ONLY from chunk-table cg (1.6 MB, L2-resident
// per XCD under dispatch%8=XCD round-robin). One node per lane; srt/cur
// staged in LDS (coalesced); per-lane 16 B uint4 gathers, 4-deep batched,
// clamped+masked for tail.
#define AGGR_BODY(GETSRC)                                                     \
    for (int j = st; j < en; j += 4) {                                        \
        unsigned u[4][4];                                                     \
        _Pragma("unroll")                                                     \
        for (int i = 0; i < 4; ++i) {                                         \
            int jj = min(j + i, en - 1);                                      \
            int sidx = GETSRC;                                                \
            const uint4 uu = *(const uint4*)(tab + (size_t)sidx * 8);         \
            unsigned m = (j + i < en) ? 0xffffffffu : 0u;                     \
            u[i][0] = uu.x & m; u[i][1] = uu.y & m;                           \
            u[i][2] = uu.z & m; u[i][3] = uu.w & m;                           \
        }                                                                     \
        _Pragma("unroll")                                                     \
        for (int i = 0; i < 4; ++i) {                                         \
            _Pragma("unroll")                                                 \
            for (int k = 0; k < 4; ++k) {                                     \
                unsigned w = u[i][k];                                         \
                acc[2 * k]     += frombf((unsigned short)w);                  \
                acc[2 * k + 1] += frombf((unsigned short)(w >> 16));          \
            }                                                                 \
        }                                                                     \
    }

__global__ __launch_bounds__(256) void k_aggr(const unsigned short* __restrict__ hb,
                                              const int* __restrict__ cur,
                                              const int* __restrict__ srt,
                                              unsigned short* __restrict__ Sb) {
    __shared__ int s_srt[SPMAX];
    __shared__ int s_cur[257];
    const int cg = blockIdx.x & 7;      // column-chunk == XCD (dispatch%8)
    const int nb = blockIdx.x >> 3;
    const int n0 = nb * 256;
    const int tid = threadIdx.x;
    for (int i = tid; i < 257; i += 256) {
        int n = n0 + i - 1;
        s_cur[i] = (n < 0) ? 0 : cur[min(n, NN - 1)];
    }
    __syncthreads();
    const int base = s_cur[0];
    const int span = s_cur[256] - base;
    const int sp = min(span, SPMAX);
    for (int i = tid; i < sp; i += 256) s_srt[i] = srt[base + i];
    __syncthreads();
    const int n = n0 + tid;
    if (n >= NN) return;
    const int st = s_cur[tid];
    const int en = s_cur[tid + 1];
    const unsigned short* tab = hb + (size_t)cg * (NN * 8);
    float acc[8];
#pragma unroll
    for (int i = 0; i < 8; ++i) acc[i] = 0.f;

    if (span <= SPMAX) {
        AGGR_BODY(s_srt[jj - base])
    } else {
        // essentially never taken (mean span 2048, sigma ~45)
        AGGR_BODY(srt[jj])
    }

    unsigned o0 = (unsigned)tobf(acc[0]) | ((unsigned)tobf(acc[1]) << 16);
    unsigned o1 = (unsigned)tobf(acc[2]) | ((unsigned)tobf(acc[3]) << 16);
    unsigned o2 = (unsigned)tobf(acc[4]) | ((unsigned)tobf(acc[5]) << 16);
    unsigned o3 = (unsigned)tobf(acc[6]) | ((unsigned)tobf(acc[7]) << 16);
    uint4 ov; ov.x = o0; ov.y = o1; ov.z = o2; ov.w = o3;
    *(uint4*)(Sb + ((size_t)cg * NN + n) * 8) = ov;   // 16 B/lane, node-contiguous
}

// convert 8 consecutive fp32 -> bf16x8 fragment
__device__ __forceinline__ s8v cvt8(const float* __restrict__ p) {
    s8v r;
#pragma unroll
    for (int i = 0; i < 8; ++i) r[i] = (short)tobf(p[i]);
    return r;
}

// MFMA GRU: h(inplace fp32) = GRU(Sb, h); also writes bf16 shadow hb (chunked).
// NO LDS: B-fragments straight from global (24 KB, L2-resident per XCD).
// Grid 1563: every wave does exactly ONE group. __launch_bounds__(256) ONLY.
// Sb now chunk-layout: quad's 16 lanes read 256 B contiguous (better than the
// old stride-128B row reads).
__global__ __launch_bounds__(256) void k_gru(const unsigned short* __restrict__ Sb,
                                             float* __restrict__ h,
                                             unsigned short* __restrict__ hb,
                                             const unsigned short* __restrict__ Wcp_t,
                                             const unsigned short* __restrict__ Whp,
                                             const float* __restrict__ b_ih,
                                             const float* __restrict__ b_hh) {
    const s8v* wiB = (const s8v*)Wcp_t;   // frag index (T*2+kh)*64 + lane
    const s8v* whB = (const s8v*)Whp;

    int lane = threadIdx.x & 63;
    int wave = threadIdx.x >> 6;
    int quad = lane >> 4, nidx = lane & 15;
    int g = blockIdx.x * 4 + wave;
    if (g >= NGRP) return;

    float brz[4], bzz[4], bin[4], bhn[4];
#pragma unroll
    for (int t = 0; t < 4; ++t) {
        int c = t * 16 + nidx;
        brz[t] = b_ih[c] + b_hh[c];
        bzz[t] = b_ih[64 + c] + b_hh[64 + c];
        bin[t] = b_ih[128 + c];
        bhn[t] = b_hh[128 + c];
    }

    int n0 = g * 16;
    size_t rowoff = (size_t)(n0 + nidx) * HH + quad * 8;      // fp32 h (row-major)
    size_t soff   = ((size_t)quad * NN + (n0 + nidx)) * 8;    // Sb chunk layout
    s8v aS0 = *(const s8v*)(Sb + soff);
    s8v aS1 = *(const s8v*)(Sb + soff + (size_t)4 * NN * 8);
    s8v aH0 = cvt8(h + rowoff);
    s8v aH1 = cvt8(h + rowoff + 32);

#pragma unroll
    for (int t = 0; t < 4; ++t) {
        f4v aRZ0 = {brz[t], brz[t], brz[t], brz[t]};
        f4v aRZ1 = {bzz[t], bzz[t], bzz[t], bzz[t]};
        f4v aIN  = {bin[t], bin[t], bin[t], bin[t]};
        f4v aHN  = {bhn[t], bhn[t], bhn[t], bhn[t]};
        aRZ0 = __builtin_amdgcn_mfma_f32_16x16x32_bf16(aS0, wiB[(t * 2 + 0) * 64 + lane], aRZ0, 0, 0, 0);
        aRZ0 = __builtin_amdgcn_mfma_f32_16x16x32_bf16(aS1, wiB[(t * 2 + 1) * 64 + lane], aRZ0, 0, 0, 0);
        aRZ0 = __builtin_amdgcn_mfma_f32_16x16x32_bf16(aH0, whB[(t * 2 + 0) * 64 + lane], aRZ0, 0, 0, 0);
        aRZ0 = __builtin_amdgcn_mfma_f32_16x16x32_bf16(aH1, whB[(t * 2 + 1) * 64 + lane], aRZ0, 0, 0, 0);
        int tz = t + 4;
        aRZ1 = __builtin_amdgcn_mfma_f32_16x16x32_bf16(aS0, wiB[(tz * 2 + 0) * 64 + lane], aRZ1, 0, 0, 0);
        aRZ1 = __builtin_amdgcn_mfma_f32_16x16x32_bf16(aS1, wiB[(tz * 2 + 1) * 64 + lane], aRZ1, 0, 0, 0);
        aRZ1 = __builtin_amdgcn_mfma_f32_16x16x32_bf16(aH0, whB[(tz * 2 + 0) * 64 + lane], aRZ1, 0, 0, 0);
        aRZ1 = __builtin_amdgcn_mfma_f32_16x16x32_bf16(aH1, whB[(tz * 2 + 1) * 64 + lane], aRZ1, 0, 0, 0);
        int tn = t + 8;
        aIN = __builtin_amdgcn_mfma_f32_16x16x32_bf16(aS0, wiB[(tn * 2 + 0) * 64 + lane], aIN, 0, 0, 0);
        aIN = __builtin_amdgcn_mfma_f32_16x16x32_bf16(aS1, wiB[(tn * 2 + 1) * 64 + lane], aIN, 0, 0, 0);
        aHN = __builtin_amdgcn_mfma_f32_16x16x32_bf16(aH0, whB[(tn * 2 + 0) * 64 + lane], aHN, 0, 0, 0);
        aHN = __builtin_amdgcn_mfma_f32_16x16x32_bf16(aH1, whB[(tn * 2 + 1) * 64 + lane], aHN, 0, 0, 0);
        int c = t * 16 + nidx;
        int chunk = c >> 3;
        int cc = c & 7;
#pragma unroll
        for (int reg = 0; reg < 4; ++reg) {
            int node = n0 + quad * 4 + reg;
            float rv = sigf(aRZ0[reg]);
            float zv = sigf(aRZ1[reg]);
            float nv = tanhfast(fmaf(rv, aHN[reg], aIN[reg]));
            size_t off = (size_t)node * HH + c;
            float ho = h[off];
            float hnew = fmaf(zv, ho - nv, nv);   // (1-z)n + z h
            h[off] = hnew;
            hb[((size_t)chunk * NN + node) * 8 + cc] = tobf(hnew);
        }
    }
}

// out[i] = sigmoid(dot(h[idx[i]], W_lin) + b_lin)
__global__ __launch_bounds__(256) void k_readout(const float* __restrict__ h,
                                                 const int* __restrict__ idx,
                                                 const float* __restrict__ Wl,
                                                 const float* __restrict__ bl,
                                                 float* __restrict__ out, int B) {
    int gid = blockIdx.x * 256 + threadIdx.x;
    int i = gid >> 6, lane = gid & 63;
    if (i >= B) return;
    int n = idx[i];
    float v = h[(size_t)n * HH + lane] * Wl[lane];
#pragma unroll
    for (int off = 32; off > 0; off >>= 1) v += __shfl_xor(v, off, 64);
    if (lane == 0) out[i] = sigf(v + bl[0]);
}

extern "C" void kernel_launch(void* const* d_in, const int* in_sizes, int n_in,
                              void* d_out, int out_size, void* d_ws, size_t ws_size,
                              hipStream_t stream) {
    const float* x     = (const float*)d_in[0];
    const int*   ei    = (const int*)d_in[1];
    const int*   idx   = (const int*)d_in[2];
    const float* W_red = (const float*)d_in[3];
    const float* b_red = (const float*)d_in[4];
    const float* W_g   = (const float*)d_in[5];
    const float* w_ih  = (const float*)d_in[6];
    const float* w_hh  = (const float*)d_in[7];
    const float* b_ih  = (const float*)d_in[8];
    const float* b_hh  = (const float*)d_in[9];
    const float* W_lin = (const float*)d_in[10];
    const float* b_lin = (const float*)d_in[11];
    float* out = (float*)d_out;
    const int E = in_sizes[1] / 2;
    const int B = in_sizes[2];
    const int* src = ei;
    const int* dst = ei + E;
    const int PB = (E + 255) / 256;   // place/hist blocks

    float*          h   = (float*)d_ws;                          // 25.6 MB
    unsigned short* hb  = (unsigned short*)(h + (size_t)NN * HH); // 12.8 MB (chunked [8][NN][8])
    unsigned short* Sb  = hb + (size_t)NN * HH;                   // 12.8 MB (chunked [8][NN][8])
    unsigned short* Wcp = Sb + (size_t)NN * HH;                   // 196 KB
    unsigned short* Whp = Wcp + (size_t)NSTEP * 12288;            // 24 KB
    int*            cur = (int*)(Whp + 12288);                    // 400 KB
    int*            srt = cur + NN;                               // 3.2 MB
    int*            bsum = srt + E;                               // [NB]
    // total ~54.9 MB — R15's 68 MB bucket layout overflowed ws; stay here.

    // ---- hist (+ packed weights, fused) ----
    hipMemsetAsync(cur, 0, NN * sizeof(int), stream);
    k_histwcp<<<PB + 384 + 48, 256, 0, stream>>>(dst, cur, E, PB,
                                                 W_g, w_ih, w_hh, Wcp, Whp);

    // ---- 2-phase exclusive scan ----
    k_scan1<<<NB, 256, 0, stream>>>(cur, bsum);
    k_scan3<<<NB, 256, 0, stream>>>(cur, bsum);

    // ---- FUSED node init (persistent, first) + edge placement ----
    k_plred<<<RB + PB, 256, 0, stream>>>(src, dst, cur, srt, E,
                                         x, W_red, b_red, h, hb);

    // ---- 8 propagation steps ----
    const int AGB = ((NN + 255) / 256) * 8;   // 391 node-blocks x 8 column chunks
    for (int t = 0; t < NSTEP; ++t) {
        k_aggr<<<AGB, 256, 0, stream>>>(hb, cur, srt, Sb);
        k_gru<<<1563, 256, 0, stream>>>(Sb, h, hb, Wcp + (size_t)t * 12288, Whp,
                                        b_ih, b_hh);
    }

    k_readout<<<(B * 64 + 255) / 256, 256, 0, stream>>>(h, idx, W_lin, b_lin, out, B);
}